// Round 1
// baseline (406.957 us; speedup 1.0000x reference)
//
#include <hip/hip_runtime.h>
#include <hip/hip_bf16.h>
#include <stdint.h>

#define S_LEN 2048
#define EMB   1024
#define NH    16
#define HD    64

typedef unsigned short u16;
typedef __attribute__((ext_vector_type(4))) float f32x4;
typedef __attribute__((ext_vector_type(8))) short bf16x8;

typedef __attribute__((address_space(1))) const unsigned char gas_t;
typedef __attribute__((address_space(3))) unsigned char las_t;

static __device__ __forceinline__ void gld_lds16(const void* g, void* l) {
  __builtin_amdgcn_global_load_lds((gas_t*)g, (las_t*)l, 16, 0, 0);
}

static __device__ __forceinline__ u16 f2bf(float f) {
  unsigned int u = __builtin_bit_cast(unsigned int, f);
  u = u + 0x7fffu + ((u >> 16) & 1u);   // RNE; inputs are finite
  return (u16)(u >> 16);
}

// ---------------- x f32 -> bf16 ----------------
__global__ __launch_bounds__(256) void k_cvt(const float* __restrict__ in,
                                             u16* __restrict__ out, int n4) {
  int i = blockIdx.x * blockDim.x + threadIdx.x;
  int stride = gridDim.x * blockDim.x;
  for (; i < n4; i += stride) {
    float4 f = ((const float4*)in)[i];
    ushort4 o;
    o.x = f2bf(f.x); o.y = f2bf(f.y); o.z = f2bf(f.z); o.w = f2bf(f.w);
    ((ushort4*)out)[i] = o;
  }
}

// ---------------- W [K][N] f32 -> WT [N][K] bf16 ----------------
// grid (N/64, K/64), 256 threads
__global__ __launch_bounds__(256) void k_transpose_cvt(const float* __restrict__ W,
                                                       u16* __restrict__ WT,
                                                       int K, int N) {
  __shared__ u16 tile[64][68];
  const int c0 = blockIdx.x * 64, r0 = blockIdx.y * 64;
  const int t = threadIdx.x;
  const int tr = t >> 4, tc4 = (t & 15) * 4;
#pragma unroll
  for (int i = 0; i < 4; i++) {
    const int r = tr + 16 * i;
    float4 f = *(const float4*)&W[(size_t)(r0 + r) * N + c0 + tc4];
    ushort4 o;
    o.x = f2bf(f.x); o.y = f2bf(f.y); o.z = f2bf(f.z); o.w = f2bf(f.w);
    *(ushort4*)&tile[r][tc4] = o;
  }
  __syncthreads();
  const int oc = t >> 2, or0 = (t & 3) * 16;
  u16 vals[16];
#pragma unroll
  for (int j = 0; j < 16; j++) vals[j] = tile[or0 + j][oc];
  u16* dst = &WT[(size_t)(c0 + oc) * K + r0 + or0];
  *(uint4*)dst = *(const uint4*)&vals[0];
  *(uint4*)(dst + 8) = *(const uint4*)&vals[8];
}

// ---------------- GEMM: C[M,N] = A[M,K](bf16) @ BT[N,K]^T + bias ----------------
// 128x128 tile, BK=32, 4 waves (each 64x64 = 4x4 frags of 16x16x32)
// MODE 0: scatter q/k/v bf16 [B,H,S,D].  MODE 1: f32 out + bias.
template <int MODE>
__global__ __launch_bounds__(256) void k_gemm(const u16* __restrict__ A,
                                              const u16* __restrict__ BT,
                                              const float* __restrict__ bias,
                                              float* __restrict__ Cout,
                                              u16* __restrict__ q_ws,
                                              u16* __restrict__ k_ws,
                                              u16* __restrict__ v_ws,
                                              int N, int K) {
  __shared__ u16 As[128 * 32];
  __shared__ u16 Bs[128 * 32];
  const int tid = threadIdx.x;
  const int w = tid >> 6, lane = tid & 63;
  const int wr = w >> 1, wc = w & 1;
  const int lrow = lane & 15, lk8 = (lane >> 4) * 8;
  const int brow = blockIdx.y * 128, bcol = blockIdx.x * 128;
  const int srow = lane >> 2;          // 0..15 within chunk
  const int scol = (lane & 3) * 8;     // 0,8,16,24

  const f32x4 zero = {0.f, 0.f, 0.f, 0.f};
  f32x4 acc[4][4];
#pragma unroll
  for (int m = 0; m < 4; m++)
#pragma unroll
    for (int n = 0; n < 4; n++) acc[m][n] = zero;

  for (int kt = 0; kt < K; kt += 32) {
#pragma unroll
    for (int i = 0; i < 2; i++) {
      const int c = w * 2 + i;               // chunk 0..7, 1KB each (linear LDS)
      const int row = c * 16 + srow;
      gld_lds16(&A[(size_t)(brow + row) * K + kt + scol], (void*)(As + c * 512));
      gld_lds16(&BT[(size_t)(bcol + row) * K + kt + scol], (void*)(Bs + c * 512));
    }
    __syncthreads();
    bf16x8 af[4], bf[4];
#pragma unroll
    for (int mt = 0; mt < 4; mt++)
      af[mt] = *(const bf16x8*)&As[(wr * 64 + mt * 16 + lrow) * 32 + lk8];
#pragma unroll
    for (int nt = 0; nt < 4; nt++)
      bf[nt] = *(const bf16x8*)&Bs[(wc * 64 + nt * 16 + lrow) * 32 + lk8];
#pragma unroll
    for (int mt = 0; mt < 4; mt++)
#pragma unroll
      for (int nt = 0; nt < 4; nt++)
        acc[mt][nt] = __builtin_amdgcn_mfma_f32_16x16x32_bf16(af[mt], bf[nt],
                                                              acc[mt][nt], 0, 0, 0);
    __syncthreads();
  }

#pragma unroll
  for (int mt = 0; mt < 4; mt++)
#pragma unroll
    for (int nt = 0; nt < 4; nt++)
#pragma unroll
      for (int r = 0; r < 4; r++) {
        const int row = brow + wr * 64 + mt * 16 + (lane >> 4) * 4 + r;
        const int col = bcol + wc * 64 + nt * 16 + lrow;
        const float v = acc[mt][nt][r] + bias[col];
        if constexpr (MODE == 0) {
          const int which = col >> 10;
          const int e = col & 1023;
          const int h = e >> 6, d = e & 63;
          const int b = row >> 11, s = row & 2047;
          u16* dst = (which == 0) ? q_ws : (which == 1) ? k_ws : v_ws;
          dst[(((size_t)(b * NH + h)) * S_LEN + s) * HD + d] = f2bf(v);
        } else {
          Cout[(size_t)row * N + col] = v;
        }
      }
}

// ---------------- causal flash attention ----------------
// grid (S/64, B*H), 256 threads; wave w owns q rows [w*16, w*16+16)
__global__ __launch_bounds__(256) void k_attn(const u16* __restrict__ q_ws,
                                              const u16* __restrict__ k_ws,
                                              const u16* __restrict__ v_ws,
                                              u16* __restrict__ y) {
  __shared__ u16 Kl[64 * 64];        // XOR-swizzled rows (16B blocks)
  __shared__ u16 Vl[64 * 88];        // transposed V: [d][kv], padded
  __shared__ u16 Pl[4][16 * 64];     // per-wave P, XOR-swizzled
  const int tid = threadIdx.x;
  const int w = tid >> 6, lane = tid & 63;
  const int lrow = lane & 15, lk8 = (lane >> 4) * 8;
  const int qrow_t = (lane >> 4) * 4;
  const int ib = blockIdx.x, bh = blockIdx.y;
  const size_t base = (size_t)bh * S_LEN * HD;
  const int q0 = ib * 64;

  bf16x8 qf[2];
#pragma unroll
  for (int ks = 0; ks < 2; ks++)
    qf[ks] = *(const bf16x8*)&q_ws[base + (size_t)(q0 + w * 16 + lrow) * HD + ks * 32 + lk8];

  const f32x4 zero = {0.f, 0.f, 0.f, 0.f};
  f32x4 o_acc[4];
#pragma unroll
  for (int dt = 0; dt < 4; dt++) o_acc[dt] = zero;
  float m_run[4], l_run[4];
#pragma unroll
  for (int r = 0; r < 4; r++) { m_run[r] = -1e30f; l_run[r] = 0.f; }

  for (int jb = 0; jb <= ib; jb++) {
    const int kv0 = jb * 64;
    // K tile: global_load_lds, bank-swizzle via pre-swizzled global source
#pragma unroll
    for (int i = 0; i < 2; i++) {
      const int c = w * 2 + i;
      const int row = c * 8 + (lane >> 3);
      const int blk = (lane & 7) ^ (row & 7);
      gld_lds16(&k_ws[base + (size_t)(kv0 + row) * HD + blk * 8], (void*)(Kl + c * 512));
    }
    // V tile transposed (reg-staged); consecutive lanes write consecutive kv
#pragma unroll
    for (int i = 0; i < 2; i++) {
      const int s = i * 256 + tid;
      const int kv = s & 63;
      const int d0 = (s >> 6) * 8;
      uint4 raw = *(const uint4*)&v_ws[base + (size_t)(kv0 + kv) * HD + d0];
      const u16* tp = (const u16*)&raw;
#pragma unroll
      for (int j = 0; j < 8; j++) Vl[(d0 + j) * 88 + kv] = tp[j];
    }
    __syncthreads();

    // S = Q K^T (per wave: 16 q x 64 kv)
    f32x4 sa[4];
#pragma unroll
    for (int nt = 0; nt < 4; nt++) sa[nt] = zero;
#pragma unroll
    for (int ks = 0; ks < 2; ks++)
#pragma unroll
      for (int nt = 0; nt < 4; nt++) {
        const int kvr = nt * 16 + lrow;
        const int blk = (ks * 4 + (lane >> 4)) ^ (kvr & 7);
        bf16x8 kf = *(const bf16x8*)((const char*)Kl + kvr * 128 + blk * 16);
        sa[nt] = __builtin_amdgcn_mfma_f32_16x16x32_bf16(qf[ks], kf, sa[nt], 0, 0, 0);
      }

    float sv[4][4];
#pragma unroll
    for (int nt = 0; nt < 4; nt++)
#pragma unroll
      for (int r = 0; r < 4; r++) {
        float x = sa[nt][r] * 0.125f;  // D^-0.5
        if (jb == ib && (nt * 16 + lrow) > (w * 16 + qrow_t + r)) x = -1e30f;
        sv[nt][r] = x;
      }

    // online softmax (rows live in 16-lane groups)
#pragma unroll
    for (int r = 0; r < 4; r++) {
      float mx = fmaxf(fmaxf(sv[0][r], sv[1][r]), fmaxf(sv[2][r], sv[3][r]));
      mx = fmaxf(mx, __shfl_xor(mx, 1));
      mx = fmaxf(mx, __shfl_xor(mx, 2));
      mx = fmaxf(mx, __shfl_xor(mx, 4));
      mx = fmaxf(mx, __shfl_xor(mx, 8));
      const float mn = fmaxf(m_run[r], mx);
      const float alpha = __expf(m_run[r] - mn);
      float sum = 0.f;
#pragma unroll
      for (int nt = 0; nt < 4; nt++) {
        const float p = __expf(sv[nt][r] - mn);
        sv[nt][r] = p;
        sum += p;
      }
      sum += __shfl_xor(sum, 1);
      sum += __shfl_xor(sum, 2);
      sum += __shfl_xor(sum, 4);
      sum += __shfl_xor(sum, 8);
      l_run[r] = l_run[r] * alpha + sum;
      m_run[r] = mn;
#pragma unroll
      for (int dt = 0; dt < 4; dt++) o_acc[dt][r] *= alpha;
    }

    // P -> per-wave LDS (bf16, swizzled)
    u16* Pw = &Pl[w][0];
#pragma unroll
    for (int nt = 0; nt < 4; nt++)
#pragma unroll
      for (int r = 0; r < 4; r++) {
        const int row = qrow_t + r;
        const int col = nt * 16 + lrow;
        *(u16*)((char*)Pw + row * 128 + ((col * 2) ^ ((row & 7) << 4))) = f2bf(sv[nt][r]);
      }

    // O += P @ V
#pragma unroll
    for (int ks = 0; ks < 2; ks++) {
      const int blk = (ks * 4 + (lane >> 4)) ^ (lrow & 7);
      bf16x8 pf = *(const bf16x8*)((const char*)Pw + lrow * 128 + blk * 16);
#pragma unroll
      for (int dt = 0; dt < 4; dt++) {
        bf16x8 vf = *(const bf16x8*)&Vl[(dt * 16 + lrow) * 88 + ks * 32 + lk8];
        o_acc[dt] = __builtin_amdgcn_mfma_f32_16x16x32_bf16(pf, vf, o_acc[dt], 0, 0, 0);
      }
    }
    __syncthreads();
  }

  const int b = bh >> 4, h = bh & 15;
#pragma unroll
  for (int r = 0; r < 4; r++) {
    const float inv = 1.0f / l_run[r];
    const int qg = q0 + w * 16 + qrow_t + r;
#pragma unroll
    for (int dt = 0; dt < 4; dt++)
      y[((size_t)(b * S_LEN + qg)) * EMB + h * HD + dt * 16 + lrow] =
          f2bf(o_acc[dt][r] * inv);
  }
}

extern "C" void kernel_launch(void* const* d_in, const int* in_sizes, int n_in,
                              void* d_out, int out_size, void* d_ws, size_t ws_size,
                              hipStream_t stream) {
  const float* x      = (const float*)d_in[0];
  const float* w_qkv  = (const float*)d_in[1];
  const float* b_qkv  = (const float*)d_in[2];
  const float* w_proj = (const float*)d_in[3];
  const float* b_proj = (const float*)d_in[4];
  float* out = (float*)d_out;

  char* ws = (char*)d_ws;
  u16* wqkvT  = (u16*)(ws);                  // 3072x1024 bf16 (6 MB)
  u16* wprojT = (u16*)(ws + 6291456);        // 1024x1024 bf16 (2 MB)
  u16* xb     = (u16*)(ws + 8388608);        // 8192x1024 bf16 (16 MB), reused as y_att
  u16* q_ws   = (u16*)(ws + 25165824);       // [B,H,S,D] bf16 (16 MB)
  u16* k_ws   = (u16*)(ws + 41943040);
  u16* v_ws   = (u16*)(ws + 58720256);       // end: 72 MB
  u16* y_att  = xb;                          // x dead after GEMM1

  k_cvt<<<dim3(1024), dim3(256), 0, stream>>>(x, xb, (8192 * 1024) / 4);
  k_transpose_cvt<<<dim3(48, 16), dim3(256), 0, stream>>>(w_qkv, wqkvT, 1024, 3072);
  k_transpose_cvt<<<dim3(16, 16), dim3(256), 0, stream>>>(w_proj, wprojT, 1024, 1024);
  k_gemm<0><<<dim3(24, 64), dim3(256), 0, stream>>>(xb, wqkvT, b_qkv, nullptr,
                                                    q_ws, k_ws, v_ws, 3072, 1024);
  k_attn<<<dim3(32, 64), dim3(256), 0, stream>>>(q_ws, k_ws, v_ws, y_att);
  k_gemm<1><<<dim3(8, 64), dim3(256), 0, stream>>>(y_att, wprojT, b_proj, out,
                                                   nullptr, nullptr, nullptr, 1024, 1024);
}

// Round 2
// 261.636 us; speedup vs baseline: 1.5554x; 1.5554x over previous
//
#include <hip/hip_runtime.h>
#include <hip/hip_bf16.h>
#include <stdint.h>

#define S_LEN 2048
#define EMB   1024
#define NH    16
#define HD    64

typedef unsigned short u16;
typedef __attribute__((ext_vector_type(4))) float f32x4;
typedef __attribute__((ext_vector_type(8))) short bf16x8;

typedef __attribute__((address_space(1))) const unsigned char gas_t;
typedef __attribute__((address_space(3))) unsigned char las_t;

static __device__ __forceinline__ void gld_lds16(const void* g, void* l) {
  __builtin_amdgcn_global_load_lds((gas_t*)g, (las_t*)l, 16, 0, 0);
}

static __device__ __forceinline__ u16 f2bf(float f) {
  unsigned int u = __builtin_bit_cast(unsigned int, f);
  u = u + 0x7fffu + ((u >> 16) & 1u);   // RNE; inputs are finite
  return (u16)(u >> 16);
}

// ---------------- x f32 -> bf16 ----------------
__global__ __launch_bounds__(256) void k_cvt(const float* __restrict__ in,
                                             u16* __restrict__ out, int n4) {
  int i = blockIdx.x * blockDim.x + threadIdx.x;
  int stride = gridDim.x * blockDim.x;
  for (; i < n4; i += stride) {
    float4 f = ((const float4*)in)[i];
    ushort4 o;
    o.x = f2bf(f.x); o.y = f2bf(f.y); o.z = f2bf(f.z); o.w = f2bf(f.w);
    ((ushort4*)out)[i] = o;
  }
}

// ---------------- W [K][N] f32 -> WT [N][K] bf16 ----------------
// grid (N/64, K/64), 256 threads
__global__ __launch_bounds__(256) void k_transpose_cvt(const float* __restrict__ W,
                                                       u16* __restrict__ WT,
                                                       int K, int N) {
  __shared__ u16 tile[64][68];
  const int c0 = blockIdx.x * 64, r0 = blockIdx.y * 64;
  const int t = threadIdx.x;
  const int tr = t >> 4, tc4 = (t & 15) * 4;
#pragma unroll
  for (int i = 0; i < 4; i++) {
    const int r = tr + 16 * i;
    float4 f = *(const float4*)&W[(size_t)(r0 + r) * N + c0 + tc4];
    ushort4 o;
    o.x = f2bf(f.x); o.y = f2bf(f.y); o.z = f2bf(f.z); o.w = f2bf(f.w);
    *(ushort4*)&tile[r][tc4] = o;
  }
  __syncthreads();
  const int oc = t >> 2, or0 = (t & 3) * 16;
  u16 vals[16];
#pragma unroll
  for (int j = 0; j < 16; j++) vals[j] = tile[or0 + j][oc];
  u16* dst = &WT[(size_t)(c0 + oc) * K + r0 + or0];
  *(uint4*)dst = *(const uint4*)&vals[0];
  *(uint4*)(dst + 8) = *(const uint4*)&vals[8];
}

// ---------------- GEMM: C[M,N] = A[M,K](bf16) @ BT[N,K]^T + bias ----------------
// 128x128 tile, BK=32, 4 waves (each 64x64 = 4x4 frags of 16x16x32)
// MODE 0: scatter q/k bf16 [B,H,S,D], v bf16 [B,H,D,S] (transposed, vectorized).
// MODE 1: f32 out + bias.
template <int MODE>
__global__ __launch_bounds__(256) void k_gemm(const u16* __restrict__ A,
                                              const u16* __restrict__ BT,
                                              const float* __restrict__ bias,
                                              float* __restrict__ Cout,
                                              u16* __restrict__ q_ws,
                                              u16* __restrict__ k_ws,
                                              u16* __restrict__ v_t,
                                              int N, int K) {
  __shared__ u16 As[128 * 32];
  __shared__ u16 Bs[128 * 32];
  const int tid = threadIdx.x;
  const int w = tid >> 6, lane = tid & 63;
  const int wr = w >> 1, wc = w & 1;
  const int lrow = lane & 15, lk8 = (lane >> 4) * 8;
  const int brow = blockIdx.y * 128, bcol = blockIdx.x * 128;
  const int srow = lane >> 2;          // 0..15 within chunk
  const int scol = (lane & 3) * 8;     // 0,8,16,24

  const f32x4 zero = {0.f, 0.f, 0.f, 0.f};
  f32x4 acc[4][4];
#pragma unroll
  for (int m = 0; m < 4; m++)
#pragma unroll
    for (int n = 0; n < 4; n++) acc[m][n] = zero;

  for (int kt = 0; kt < K; kt += 32) {
#pragma unroll
    for (int i = 0; i < 2; i++) {
      const int c = w * 2 + i;               // chunk 0..7, 1KB each (linear LDS)
      const int row = c * 16 + srow;
      gld_lds16(&A[(size_t)(brow + row) * K + kt + scol], (void*)(As + c * 512));
      gld_lds16(&BT[(size_t)(bcol + row) * K + kt + scol], (void*)(Bs + c * 512));
    }
    __syncthreads();
    bf16x8 af[4], bfr[4];
#pragma unroll
    for (int mt = 0; mt < 4; mt++)
      af[mt] = *(const bf16x8*)&As[(wr * 64 + mt * 16 + lrow) * 32 + lk8];
#pragma unroll
    for (int nt = 0; nt < 4; nt++)
      bfr[nt] = *(const bf16x8*)&Bs[(wc * 64 + nt * 16 + lrow) * 32 + lk8];
    __builtin_amdgcn_s_setprio(1);
#pragma unroll
    for (int mt = 0; mt < 4; mt++)
#pragma unroll
      for (int nt = 0; nt < 4; nt++)
        acc[mt][nt] = __builtin_amdgcn_mfma_f32_16x16x32_bf16(af[mt], bfr[nt],
                                                              acc[mt][nt], 0, 0, 0);
    __builtin_amdgcn_s_setprio(0);
    __syncthreads();
  }

  if constexpr (MODE == 0) {
    const int which = bcol >> 10;   // uniform per block (0=q, 1=k, 2=v)
#pragma unroll
    for (int mt = 0; mt < 4; mt++)
#pragma unroll
      for (int nt = 0; nt < 4; nt++) {
        const int col = bcol + wc * 64 + nt * 16 + lrow;
        const int e = col & 1023;
        const int h = e >> 6, d = e & 63;
        const int row0 = brow + wr * 64 + mt * 16 + (lane >> 4) * 4;
        const int b = row0 >> 11, s0 = row0 & 2047;
        const size_t bh = (size_t)(b * NH + h);
        const float bv = bias[col];
        if (which == 2) {
          ushort4 pk;
          pk.x = f2bf(acc[mt][nt][0] + bv);
          pk.y = f2bf(acc[mt][nt][1] + bv);
          pk.z = f2bf(acc[mt][nt][2] + bv);
          pk.w = f2bf(acc[mt][nt][3] + bv);
          *(ushort4*)&v_t[(bh * HD + d) * S_LEN + s0] = pk;
        } else {
          u16* dst = which ? k_ws : q_ws;
#pragma unroll
          for (int r = 0; r < 4; r++)
            dst[(bh * S_LEN + s0 + r) * HD + d] = f2bf(acc[mt][nt][r] + bv);
        }
      }
  } else {
#pragma unroll
    for (int mt = 0; mt < 4; mt++)
#pragma unroll
      for (int nt = 0; nt < 4; nt++)
#pragma unroll
        for (int r = 0; r < 4; r++) {
          const int row = brow + wr * 64 + mt * 16 + (lane >> 4) * 4 + r;
          const int col = bcol + wc * 64 + nt * 16 + lrow;
          Cout[(size_t)row * N + col] = acc[mt][nt][r] + bias[col];
        }
  }
}

// ---------------- causal flash attention (pair-balanced) ----------------
// grid (16, B*H), 256 threads. Block pr handles q-tiles {pr, 31-pr} (64 rows
// each); K/V staged once per jb for both. Wave w owns rows [w*16,w*16+16).
// V is pre-transposed in global ([b,h,d,s]) so staging mirrors K exactly.
__global__ __launch_bounds__(256) void k_attn(const u16* __restrict__ q_ws,
                                              const u16* __restrict__ k_ws,
                                              const u16* __restrict__ v_t,
                                              u16* __restrict__ y) {
  __shared__ u16 Kl[64 * 64];        // XOR-swizzled rows (16B blocks), [kv][d]
  __shared__ u16 Vl[64 * 64];        // XOR-swizzled rows, [d][kv]
  __shared__ u16 Pl[4][16 * 64];     // per-wave P, XOR-swizzled
  const int tid = threadIdx.x;
  const int w = tid >> 6, lane = tid & 63;
  const int lrow = lane & 15, lk8 = (lane >> 4) * 8;
  const int qrow_t = (lane >> 4) * 4;
  const int pr = blockIdx.x;               // 0..15
  const int tileA = pr, tileB = 31 - pr;   // tileA < tileB, work = const 33
  const int bh = blockIdx.y;
  const size_t base = (size_t)bh * S_LEN * HD;

  bf16x8 qfA[2], qfB[2];
#pragma unroll
  for (int ks = 0; ks < 2; ks++) {
    qfA[ks] = *(const bf16x8*)&q_ws[base + (size_t)(tileA * 64 + w * 16 + lrow) * HD + ks * 32 + lk8];
    qfB[ks] = *(const bf16x8*)&q_ws[base + (size_t)(tileB * 64 + w * 16 + lrow) * HD + ks * 32 + lk8];
  }

  const f32x4 zero = {0.f, 0.f, 0.f, 0.f};
  f32x4 oA[4], oB[4];
#pragma unroll
  for (int dt = 0; dt < 4; dt++) { oA[dt] = zero; oB[dt] = zero; }
  float mA[4], lA[4], mB[4], lB[4];
#pragma unroll
  for (int r = 0; r < 4; r++) { mA[r] = -1e30f; lA[r] = 0.f; mB[r] = -1e30f; lB[r] = 0.f; }

  u16* Pw = &Pl[w][0];

  auto process = [&](const bf16x8 (&qf)[2], f32x4 (&o)[4], float (&m_run)[4],
                     float (&l_run)[4], bool maskDiag) {
    // S = Q K^T (per wave: 16 q x 64 kv)
    f32x4 sa[4];
#pragma unroll
    for (int nt = 0; nt < 4; nt++) sa[nt] = zero;
    __builtin_amdgcn_s_setprio(1);
#pragma unroll
    for (int ks = 0; ks < 2; ks++)
#pragma unroll
      for (int nt = 0; nt < 4; nt++) {
        const int kvr = nt * 16 + lrow;
        const int blk = (ks * 4 + (lane >> 4)) ^ (kvr & 7);
        bf16x8 kf = *(const bf16x8*)((const char*)Kl + kvr * 128 + blk * 16);
        sa[nt] = __builtin_amdgcn_mfma_f32_16x16x32_bf16(qf[ks], kf, sa[nt], 0, 0, 0);
      }
    __builtin_amdgcn_s_setprio(0);

    float sv[4][4];
#pragma unroll
    for (int nt = 0; nt < 4; nt++)
#pragma unroll
      for (int r = 0; r < 4; r++) {
        float x = sa[nt][r] * 0.125f;  // D^-0.5
        if (maskDiag && (nt * 16 + lrow) > (w * 16 + qrow_t + r)) x = -1e30f;
        sv[nt][r] = x;
      }

    // online softmax (rows live in 16-lane groups)
#pragma unroll
    for (int r = 0; r < 4; r++) {
      float mx = fmaxf(fmaxf(sv[0][r], sv[1][r]), fmaxf(sv[2][r], sv[3][r]));
      mx = fmaxf(mx, __shfl_xor(mx, 1));
      mx = fmaxf(mx, __shfl_xor(mx, 2));
      mx = fmaxf(mx, __shfl_xor(mx, 4));
      mx = fmaxf(mx, __shfl_xor(mx, 8));
      const float mn = fmaxf(m_run[r], mx);
      const float alpha = __expf(m_run[r] - mn);
      float sum = 0.f;
#pragma unroll
      for (int nt = 0; nt < 4; nt++) {
        const float p = __expf(sv[nt][r] - mn);
        sv[nt][r] = p;
        sum += p;
      }
      sum += __shfl_xor(sum, 1);
      sum += __shfl_xor(sum, 2);
      sum += __shfl_xor(sum, 4);
      sum += __shfl_xor(sum, 8);
      l_run[r] = l_run[r] * alpha + sum;
      m_run[r] = mn;
#pragma unroll
      for (int dt = 0; dt < 4; dt++) o[dt][r] *= alpha;
    }

    // P -> per-wave LDS (bf16, swizzled)
#pragma unroll
    for (int nt = 0; nt < 4; nt++)
#pragma unroll
      for (int r = 0; r < 4; r++) {
        const int row = qrow_t + r;
        const int col = nt * 16 + lrow;
        *(u16*)((char*)Pw + row * 128 + ((col * 2) ^ ((row & 7) << 4))) = f2bf(sv[nt][r]);
      }

    // O += P @ V
    __builtin_amdgcn_s_setprio(1);
#pragma unroll
    for (int ks = 0; ks < 2; ks++) {
      const int blk = (ks * 4 + (lane >> 4)) ^ (lrow & 7);
      bf16x8 pf = *(const bf16x8*)((const char*)Pw + lrow * 128 + blk * 16);
#pragma unroll
      for (int dt = 0; dt < 4; dt++) {
        const int vr = dt * 16 + lrow;
        const int vblk = (ks * 4 + (lane >> 4)) ^ (vr & 7);
        bf16x8 vf = *(const bf16x8*)((const char*)Vl + vr * 128 + vblk * 16);
        o[dt] = __builtin_amdgcn_mfma_f32_16x16x32_bf16(pf, vf, o[dt], 0, 0, 0);
      }
    }
    __builtin_amdgcn_s_setprio(0);
  };

  for (int jb = 0; jb <= tileB; jb++) {
    const int kv0 = jb * 64;
    // K tile: global_load_lds, bank-swizzle via pre-swizzled global source
#pragma unroll
    for (int i = 0; i < 2; i++) {
      const int c = w * 2 + i;
      const int row = c * 8 + (lane >> 3);
      const int blk = (lane & 7) ^ (row & 7);
      gld_lds16(&k_ws[base + (size_t)(kv0 + row) * HD + blk * 8], (void*)(Kl + c * 512));
    }
    // V tile: identical pattern from pre-transposed V^T [d][s]
#pragma unroll
    for (int i = 0; i < 2; i++) {
      const int c = w * 2 + i;
      const int drow = c * 8 + (lane >> 3);
      const int blk = (lane & 7) ^ (drow & 7);
      gld_lds16(&v_t[base + (size_t)drow * S_LEN + kv0 + blk * 8], (void*)(Vl + c * 512));
    }
    __syncthreads();

    process(qfB, oB, mB, lB, jb == tileB);
    if (jb <= tileA) process(qfA, oA, mA, lA, jb == tileA);
    __syncthreads();
  }

  const int b = bh >> 4, h = bh & 15;
#pragma unroll
  for (int r = 0; r < 4; r++) {
    const float invA = 1.0f / lA[r];
    const float invB = 1.0f / lB[r];
    const int qgA = tileA * 64 + w * 16 + qrow_t + r;
    const int qgB = tileB * 64 + w * 16 + qrow_t + r;
#pragma unroll
    for (int dt = 0; dt < 4; dt++) {
      y[((size_t)(b * S_LEN + qgA)) * EMB + h * HD + dt * 16 + lrow] = f2bf(oA[dt][r] * invA);
      y[((size_t)(b * S_LEN + qgB)) * EMB + h * HD + dt * 16 + lrow] = f2bf(oB[dt][r] * invB);
    }
  }
}

extern "C" void kernel_launch(void* const* d_in, const int* in_sizes, int n_in,
                              void* d_out, int out_size, void* d_ws, size_t ws_size,
                              hipStream_t stream) {
  const float* x      = (const float*)d_in[0];
  const float* w_qkv  = (const float*)d_in[1];
  const float* b_qkv  = (const float*)d_in[2];
  const float* w_proj = (const float*)d_in[3];
  const float* b_proj = (const float*)d_in[4];
  float* out = (float*)d_out;

  char* ws = (char*)d_ws;
  u16* wqkvT  = (u16*)(ws);                  // 3072x1024 bf16 (6 MB)
  u16* wprojT = (u16*)(ws + 6291456);        // 1024x1024 bf16 (2 MB)
  u16* xb     = (u16*)(ws + 8388608);        // 8192x1024 bf16 (16 MB), reused as y_att
  u16* q_ws   = (u16*)(ws + 25165824);       // [B,H,S,D] bf16 (16 MB)
  u16* k_ws   = (u16*)(ws + 41943040);       // [B,H,S,D]
  u16* v_t    = (u16*)(ws + 58720256);       // [B,H,D,S] (transposed!)  end: 72 MB
  u16* y_att  = xb;                          // x dead after GEMM1

  k_cvt<<<dim3(1024), dim3(256), 0, stream>>>(x, xb, (8192 * 1024) / 4);
  k_transpose_cvt<<<dim3(48, 16), dim3(256), 0, stream>>>(w_qkv, wqkvT, 1024, 3072);
  k_transpose_cvt<<<dim3(16, 16), dim3(256), 0, stream>>>(w_proj, wprojT, 1024, 1024);
  k_gemm<0><<<dim3(24, 64), dim3(256), 0, stream>>>(xb, wqkvT, b_qkv, nullptr,
                                                    q_ws, k_ws, v_t, 3072, 1024);
  k_attn<<<dim3(16, 64), dim3(256), 0, stream>>>(q_ws, k_ws, v_t, y_att);
  k_gemm<1><<<dim3(8, 64), dim3(256), 0, stream>>>(y_att, wprojT, b_proj, out,
                                                   nullptr, nullptr, nullptr, 1024, 1024);
}